// Round 8
// baseline (183.719 us; speedup 1.0000x reference)
//
#include <hip/hip_runtime.h>
#include <math.h>

#define B 8
#define S 128
#define D 256
#define H 8
#define T 129
#define HD 32
#define NEG_INF -1000000000.0f
#define LN_EPS 1e-5f

// ---------------------------------------------------------------------------
// Kernel 1: ALL pre-attention GEMM work. blockIdx.x slabs:
//   [0,258)   : v = nv @ Wv + bv          (1032 rows, row-major)
//   [258,514) : U = desc @ We1_top + be1  (row-major) + row stats sU,sU2
//   [514,770) : V = desc @ We1_bot        (row-major + Vt) + row stats sV,sV2
//   [770,835) : qdkd = nv @ fold(Wq,Wk,wa) + fold(bq,bk)   (1032 x 16)
//   835       : W2ca[c*8+h] fold + econst
// ---------------------------------------------------------------------------
__global__ __launch_bounds__(256) void gemm_all(
    const float* __restrict__ nv, const float* __restrict__ desc,
    const float* __restrict__ Wq, const float* __restrict__ bq,
    const float* __restrict__ Wk, const float* __restrict__ bk,
    const float* __restrict__ Wv, const float* __restrict__ bv,
    const float* __restrict__ We1, const float* __restrict__ be1,
    const float* __restrict__ We2, const float* __restrict__ be2,
    const float* __restrict__ wa,
    float* __restrict__ v, float* __restrict__ U, float* __restrict__ V,
    float* __restrict__ Vt, float* __restrict__ qdkd,
    float* __restrict__ W2ca, float* __restrict__ econst,
    float* __restrict__ sU, float* __restrict__ sU2,
    float* __restrict__ sV, float* __restrict__ sV2)
{
    const int blk = blockIdx.x;
    const int tid = threadIdx.x;

    __shared__ float xs16[16 * 260];
    __shared__ float wq_s[4096];
    __shared__ float bq_s[16];
    __shared__ float red[4][8];

    if (blk < 770) {
        const float* X; const float* W; const float* bias; int r0; int mode;
        if (blk < 258)      { X = nv;   W = Wv;        bias = bv;      r0 = blk * 4;         mode = 0; }
        else if (blk < 514) { X = desc; W = We1;       bias = be1;     r0 = (blk - 258) * 4; mode = 1; }
        else                { X = desc; W = We1 + D*D; bias = nullptr; r0 = (blk - 514) * 4; mode = 2; }
        const int c = tid;

        const float* x0 = X + (r0 + 0) * D;
        const float* x1 = X + (r0 + 1) * D;
        const float* x2 = X + (r0 + 2) * D;
        const float* x3 = X + (r0 + 3) * D;

        float acc0 = 0.f, acc1 = 0.f, acc2 = 0.f, acc3 = 0.f;
        float w[8], nw[8];
        #pragma unroll
        for (int q = 0; q < 8; ++q) w[q] = W[q * D + c];

        for (int kk = 0; kk < 256; kk += 8) {
            const int kn = kk + 8;
            if (kn < 256) {
                #pragma unroll
                for (int q = 0; q < 8; ++q) nw[q] = W[(kn + q) * D + c];
            }
            float xv0[8], xv1[8], xv2[8], xv3[8];
            *(float4*)&xv0[0] = *(const float4*)(x0 + kk);
            *(float4*)&xv0[4] = *(const float4*)(x0 + kk + 4);
            *(float4*)&xv1[0] = *(const float4*)(x1 + kk);
            *(float4*)&xv1[4] = *(const float4*)(x1 + kk + 4);
            *(float4*)&xv2[0] = *(const float4*)(x2 + kk);
            *(float4*)&xv2[4] = *(const float4*)(x2 + kk + 4);
            *(float4*)&xv3[0] = *(const float4*)(x3 + kk);
            *(float4*)&xv3[4] = *(const float4*)(x3 + kk + 4);
            #pragma unroll
            for (int q = 0; q < 8; ++q) {
                acc0 = fmaf(xv0[q], w[q], acc0);
                acc1 = fmaf(xv1[q], w[q], acc1);
                acc2 = fmaf(xv2[q], w[q], acc2);
                acc3 = fmaf(xv3[q], w[q], acc3);
            }
            if (kn < 256) {
                #pragma unroll
                for (int q = 0; q < 8; ++q) w[q] = nw[q];
            }
        }

        const float bb = bias ? bias[c] : 0.f;
        const float o0 = acc0 + bb, o1 = acc1 + bb, o2 = acc2 + bb, o3 = acc3 + bb;

        if (mode == 0) {
            if (r0 + 0 < B*T) v[(r0 + 0) * D + c] = o0;
            if (r0 + 1 < B*T) v[(r0 + 1) * D + c] = o1;
            if (r0 + 2 < B*T) v[(r0 + 2) * D + c] = o2;
            if (r0 + 3 < B*T) v[(r0 + 3) * D + c] = o3;
        } else {
            if (mode == 1) {
                U[(r0 + 0) * D + c] = o0;
                U[(r0 + 1) * D + c] = o1;
                U[(r0 + 2) * D + c] = o2;
                U[(r0 + 3) * D + c] = o3;
            } else {
                V[(r0 + 0) * D + c] = o0;
                V[(r0 + 1) * D + c] = o1;
                V[(r0 + 2) * D + c] = o2;
                V[(r0 + 3) * D + c] = o3;
                const int b_ = r0 >> 7, rl = r0 & 127;
                float4 tv; tv.x = o0; tv.y = o1; tv.z = o2; tv.w = o3;
                *(float4*)&Vt[((size_t)b_ * D + c) * S + rl] = tv;
            }
            // ---- per-row sum / sum-of-squares epilogue ----
            float s0 = o0, s1 = o1, s2 = o2, s3 = o3;
            float q0 = o0*o0, q1 = o1*o1, q2 = o2*o2, q3 = o3*o3;
            #pragma unroll
            for (int m = 32; m >= 1; m >>= 1) {
                s0 += __shfl_xor(s0, m); q0 += __shfl_xor(q0, m);
                s1 += __shfl_xor(s1, m); q1 += __shfl_xor(q1, m);
                s2 += __shfl_xor(s2, m); q2 += __shfl_xor(q2, m);
                s3 += __shfl_xor(s3, m); q3 += __shfl_xor(q3, m);
            }
            const int wv = tid >> 6;
            if ((tid & 63) == 0) {
                red[wv][0] = s0; red[wv][1] = s1; red[wv][2] = s2; red[wv][3] = s3;
                red[wv][4] = q0; red[wv][5] = q1; red[wv][6] = q2; red[wv][7] = q3;
            }
            __syncthreads();
            if (tid < 4) {
                const float ss = red[0][tid] + red[1][tid] + red[2][tid] + red[3][tid];
                const float qq = red[0][4+tid] + red[1][4+tid] + red[2][4+tid] + red[3][4+tid];
                const int row = r0 + tid;
                if (mode == 1) { sU[row] = ss; sU2[row] = qq; }
                else           { sV[row] = ss; sV2[row] = qq; }
            }
        }
    } else if (blk < 835) {
        // ---------------- qdkd slab (self-folding) ----------------
        const int r0 = (blk - 770) * 16;
        for (int t = tid; t < 4096; t += 256) {
            const int k = t >> 4, cc = t & 15;
            const float* Wsrc = (cc < 8) ? Wq : Wk;
            const float* wap  = (cc < 8) ? wa : wa + HD;
            const int h = cc & 7;
            float s = 0.f;
            #pragma unroll
            for (int d = 0; d < HD; ++d) s = fmaf(Wsrc[k*D + h*HD + d], wap[d], s);
            wq_s[t] = s;
        }
        if (tid < 16) {
            const float* bsrc = (tid < 8) ? bq : bk;
            const float* wap  = (tid < 8) ? wa : wa + HD;
            const int h = tid & 7;
            float s = 0.f;
            #pragma unroll
            for (int d = 0; d < HD; ++d) s = fmaf(bsrc[h*HD + d], wap[d], s);
            bq_s[tid] = s;
        }
        for (int t = tid; t < 16 * 256; t += 256) {
            const int r = t >> 8, cch = t & 255, rr = r0 + r;
            xs16[r * 260 + cch] = (rr < B*T) ? nv[rr * D + cch] : 0.f;
        }
        __syncthreads();

        const int r = tid >> 4, cc = tid & 15;
        float acc = 0.f;
        for (int kk = 0; kk < 256; kk += 4) {
            const float4 x = *(const float4*)&xs16[r * 260 + kk];
            acc = fmaf(x.x, wq_s[(kk+0)*16 + cc], acc);
            acc = fmaf(x.y, wq_s[(kk+1)*16 + cc], acc);
            acc = fmaf(x.z, wq_s[(kk+2)*16 + cc], acc);
            acc = fmaf(x.w, wq_s[(kk+3)*16 + cc], acc);
        }
        const int rr = r0 + r;
        if (rr < B*T) qdkd[rr * 16 + cc] = acc + bq_s[cc];
    } else {
        // ---------------- W2ca fold (channel-major) + econst ----------------
        for (int t = tid; t < 2048; t += 256) {
            const int cch = t >> 3, h = t & 7;
            float s = 0.f;
            #pragma unroll
            for (int d = 0; d < HD; ++d) s = fmaf(We2[cch*D + h*HD + d], wa[2*HD + d], s);
            W2ca[t] = s;
        }
        if (tid < 8) {
            float s = 0.f;
            #pragma unroll
            for (int d = 0; d < HD; ++d) s = fmaf(be2[tid*HD + d], wa[2*HD + d], s);
            econst[tid] = s;
        }
    }
}

// ---------------------------------------------------------------------------
// Kernel 2 (v6): edge scores + softmax + ctx, 2-j-per-wave-step layout.
// Block = (b*T + i), 512 thr = 8 waves.
//  Phase 0: in-block UV row (i>=1: UV[i-1][j] via Vt; i==0: diag U_j.V_j).
//  Phase A: wave wid owns j = 1+wid*16 + step*2 + half (8 steps); within a
//    half-wave (32 lanes) lane owns 8 fixed channels (c0 = lane32*8).
//    w2 (8x8), g, b, U-row in registers. Per-j reduce = 9 shfl over 32 lanes.
//  Phase B: wave = head softmax (+prior bias), Phase C: ctx.
// ---------------------------------------------------------------------------
__global__ __launch_bounds__(512, 4) void edge_attn(
    const float* __restrict__ U, const float* __restrict__ V,
    const float* __restrict__ Vt,
    const float* __restrict__ W2ca, const float* __restrict__ econst,
    const float* __restrict__ ln_g, const float* __restrict__ ln_b,
    const float* __restrict__ qdkd, const float* __restrict__ prior,
    const float* __restrict__ v, const float* __restrict__ ba,
    const float* __restrict__ sU, const float* __restrict__ sU2,
    const float* __restrict__ sV, const float* __restrict__ sV2,
    float* __restrict__ out_basis, float* __restrict__ out_attn)
{
    const int bid = blockIdx.x;      // b*T + i
    const int b = bid / T, i = bid % T;
    const int tid = threadIdx.x, lane = tid & 63, wid = tid >> 6;
    const int lane32 = lane & 31, half = lane >> 5;
    const int c0 = lane32 * 8;

    __shared__ float escl[H][132];
    __shared__ float pat[H][132];
    __shared__ float uvp[4][128];
    __shared__ float uvrow[128];

    // ---- Phase 0: UV row for this i ----
    {
        const int j = tid & 127, kc = tid >> 7;
        float a = 0.f;
        if (i >= 1) {
            const float* ur = U + (size_t)(b*S + (i-1))*D + kc*64;
            const float* vt = Vt + ((size_t)b*D + kc*64)*S + j;
            #pragma unroll 4
            for (int c = 0; c < 64; c += 4) {
                const float4 u4 = *(const float4*)(ur + c);
                a = fmaf(u4.x, vt[(c+0)*S], a);
                a = fmaf(u4.y, vt[(c+1)*S], a);
                a = fmaf(u4.z, vt[(c+2)*S], a);
                a = fmaf(u4.w, vt[(c+3)*S], a);
            }
        } else {
            const float* ur = U + (size_t)(b*S + j)*D + kc*64;
            const float* vr = V + (size_t)(b*S + j)*D + kc*64;
            #pragma unroll 4
            for (int c = 0; c < 64; c += 4) {
                const float4 u4 = *(const float4*)(ur + c);
                const float4 v4 = *(const float4*)(vr + c);
                a = fmaf(u4.x, v4.x, fmaf(u4.y, v4.y, fmaf(u4.z, v4.z, fmaf(u4.w, v4.w, a))));
            }
        }
        uvp[kc][j] = a;
    }
    __syncthreads();
    if (tid < 128) uvrow[tid] = uvp[0][tid] + uvp[1][tid] + uvp[2][tid] + uvp[3][tid];
    __syncthreads();

    // ---- Phase A: edge scores ----
    float g_[8], b_[8];
    *(float4*)&g_[0] = *(const float4*)(ln_g + c0);
    *(float4*)&g_[4] = *(const float4*)(ln_g + c0 + 4);
    *(float4*)&b_[0] = *(const float4*)(ln_b + c0);
    *(float4*)&b_[4] = *(const float4*)(ln_b + c0 + 4);
    float4 w2a[8], w2b[8];
    #pragma unroll
    for (int cc = 0; cc < 8; ++cc) {
        w2a[cc] = *(const float4*)(W2ca + (c0 + cc)*8);
        w2b[cc] = *(const float4*)(W2ca + (c0 + cc)*8 + 4);
    }
    float ua[8];
    float su_i = 0.f, su2_i = 0.f;
    if (i >= 1) {
        const float* urow = U + (size_t)(b*S + (i-1))*D + c0;
        *(float4*)&ua[0] = *(const float4*)(urow);
        *(float4*)&ua[4] = *(const float4*)(urow + 4);
        su_i  = sU [b*S + i-1];
        su2_i = sU2[b*S + i-1];
    }

    const int hmap = 4*(lane32&1) + 2*((lane32>>1)&1) + ((lane32>>2)&1);
    const float ecl = (lane32 < 8) ? econst[hmap] : 0.f;

    const int j0 = 1 + wid * 16 + half;
#define PHASE_A(UEXPR, SU, SU2)                                               \
    _Pragma("unroll")                                                         \
    for (int step = 0; step < 8; ++step) {                                    \
        const int j = j0 + step * 2;                                          \
        const float svj  = sV [b*S + j-1];                                    \
        const float sv2j = sV2[b*S + j-1];                                    \
        const float cross = uvrow[j-1];                                       \
        const float mu  = ((SU) + svj) * (1.f / D);                           \
        const float ey2 = fmaf(2.f, cross, (SU2) + sv2j) * (1.f / D);         \
        const float rs  = rsqrtf(ey2 - mu*mu + LN_EPS);                       \
        float vv[8];                                                          \
        const float* vrow = V + (size_t)(b*S + (j-1))*D + c0;                 \
        *(float4*)&vv[0] = *(const float4*)(vrow);                            \
        *(float4*)&vv[4] = *(const float4*)(vrow + 4);                       \
        float ph[8] = {0.f,0.f,0.f,0.f,0.f,0.f,0.f,0.f};                      \
        _Pragma("unroll")                                                     \
        for (int cc = 0; cc < 8; ++cc) {                                      \
            const float y = (UEXPR) + vv[cc];                                 \
            float t = fmaf((y - mu) * rs, g_[cc], b_[cc]);                    \
            t = fmaxf(t, 0.f);                                                \
            ph[0] = fmaf(t, w2a[cc].x, ph[0]);                                \
            ph[1] = fmaf(t, w2a[cc].y, ph[1]);                                \
            ph[2] = fmaf(t, w2a[cc].z, ph[2]);                                \
            ph[3] = fmaf(t, w2a[cc].w, ph[3]);                                \
            ph[4] = fmaf(t, w2b[cc].x, ph[4]);                                \
            ph[5] = fmaf(t, w2b[cc].y, ph[5]);                                \
            ph[6] = fmaf(t, w2b[cc].z, ph[6]);                                \
            ph[7] = fmaf(t, w2b[cc].w, ph[7]);                                \
        }                                                                     \
        {                                                                     \
            const bool hi = (lane32 & 1);                                     \
            float k0 = hi ? ph[4] : ph[0], d0 = hi ? ph[0] : ph[4];           \
            float k1 = hi ? ph[5] : ph[1], d1 = hi ? ph[1] : ph[5];           \
            float k2 = hi ? ph[6] : ph[2], d2 = hi ? ph[2] : ph[6];           \
            float k3 = hi ? ph[7] : ph[3], d3 = hi ? ph[3] : ph[7];           \
            ph[0] = k0 + __shfl_xor(d0, 1);                                   \
            ph[1] = k1 + __shfl_xor(d1, 1);                                   \
            ph[2] = k2 + __shfl_xor(d2, 1);                                   \
            ph[3] = k3 + __shfl_xor(d3, 1);                                   \
        }                                                                     \
        {                                                                     \
            const bool hi = (lane32 & 2);                                     \
            float k0 = hi ? ph[2] : ph[0], d0 = hi ? ph[0] : ph[2];           \
            float k1 = hi ? ph[3] : ph[1], d1 = hi ? ph[1] : ph[3];           \
            ph[0] = k0 + __shfl_xor(d0, 2);                                   \
            ph[1] = k1 + __shfl_xor(d1, 2);                                   \
        }                                                                     \
        {                                                                     \
            const bool hi = (lane32 & 4);                                     \
            float k0 = hi ? ph[1] : ph[0], d0 = hi ? ph[0] : ph[1];           \
            ph[0] = k0 + __shfl_xor(d0, 4);                                   \
        }                                                                     \
        ph[0] += __shfl_xor(ph[0], 8);                                        \
        ph[0] += __shfl_xor(ph[0], 16);                                       \
        if (lane32 < 8) escl[hmap][j] = ph[0] + ecl;                          \
    }

    if (i >= 1) {
        PHASE_A(ua[cc], su_i, su2_i)
    } else {
        // i == 0: u row = U[j-1]; per-j stats from sU
        #pragma unroll
        for (int step = 0; step < 8; ++step) {
            const int j = j0 + step * 2;
            const float svj  = sV [b*S + j-1];
            const float sv2j = sV2[b*S + j-1];
            const float suj  = sU [b*S + j-1];
            const float su2j = sU2[b*S + j-1];
            const float cross = uvrow[j-1];
            const float mu  = (suj + svj) * (1.f / D);
            const float ey2 = fmaf(2.f, cross, su2j + sv2j) * (1.f / D);
            const float rs  = rsqrtf(ey2 - mu*mu + LN_EPS);
            float vv[8], uu[8];
            const float* vrow = V + (size_t)(b*S + (j-1))*D + c0;
            const float* urow = U + (size_t)(b*S + (j-1))*D + c0;
            *(float4*)&vv[0] = *(const float4*)(vrow);
            *(float4*)&vv[4] = *(const float4*)(vrow + 4);
            *(float4*)&uu[0] = *(const float4*)(urow);
            *(float4*)&uu[4] = *(const float4*)(urow + 4);
            float ph[8] = {0.f,0.f,0.f,0.f,0.f,0.f,0.f,0.f};
            #pragma unroll
            for (int cc = 0; cc < 8; ++cc) {
                const float y = uu[cc] + vv[cc];
                float t = fmaf((y - mu) * rs, g_[cc], b_[cc]);
                t = fmaxf(t, 0.f);
                ph[0] = fmaf(t, w2a[cc].x, ph[0]);
                ph[1] = fmaf(t, w2a[cc].y, ph[1]);
                ph[2] = fmaf(t, w2a[cc].z, ph[2]);
                ph[3] = fmaf(t, w2a[cc].w, ph[3]);
                ph[4] = fmaf(t, w2b[cc].x, ph[4]);
                ph[5] = fmaf(t, w2b[cc].y, ph[5]);
                ph[6] = fmaf(t, w2b[cc].z, ph[6]);
                ph[7] = fmaf(t, w2b[cc].w, ph[7]);
            }
            {
                const bool hi = (lane32 & 1);
                float k0 = hi ? ph[4] : ph[0], d0 = hi ? ph[0] : ph[4];
                float k1 = hi ? ph[5] : ph[1], d1 = hi ? ph[1] : ph[5];
                float k2 = hi ? ph[6] : ph[2], d2 = hi ? ph[2] : ph[6];
                float k3 = hi ? ph[7] : ph[3], d3 = hi ? ph[3] : ph[7];
                ph[0] = k0 + __shfl_xor(d0, 1);
                ph[1] = k1 + __shfl_xor(d1, 1);
                ph[2] = k2 + __shfl_xor(d2, 1);
                ph[3] = k3 + __shfl_xor(d3, 1);
            }
            {
                const bool hi = (lane32 & 2);
                float k0 = hi ? ph[2] : ph[0], d0 = hi ? ph[0] : ph[2];
                float k1 = hi ? ph[3] : ph[1], d1 = hi ? ph[1] : ph[3];
                ph[0] = k0 + __shfl_xor(d0, 2);
                ph[1] = k1 + __shfl_xor(d1, 2);
            }
            {
                const bool hi = (lane32 & 4);
                float k0 = hi ? ph[1] : ph[0], d0 = hi ? ph[0] : ph[1];
                ph[0] = k0 + __shfl_xor(d0, 4);
            }
            ph[0] += __shfl_xor(ph[0], 8);
            ph[0] += __shfl_xor(ph[0], 16);
            if (lane32 < 8) escl[hmap][j] = ph[0] + ecl;
        }
    }
#undef PHASE_A
    __syncthreads();

    // ---- Phase B: softmax (wave = head) ----
    const int h = wid;
    const int bh = b*H + h;
    const float qdv = qdkd[(b*T + i)*16 + h];
    const float ba0 = ba[0];
    const int j1 = 1 + lane, j2 = 65 + lane;
    const bool v1 = !(i >= 1 && j1 == i);
    const bool v2 = !(i >= 1 && j2 == i);

    float l1 = NEG_INF, l2 = NEG_INF;
    if (v1) {
        l1 = qdv + qdkd[(b*T + j1)*16 + 8 + h] + escl[h][j1] + ba0;
        if (i >= 1) {
            float pr = prior[((size_t)bh*S + (i-1))*S + (j1-1)];
            pr = fminf(fmaxf(pr, 1e-6f), 1.f - 1e-6f);
            l1 += __logf(pr) - __logf(1.f - pr);
        }
    }
    if (v2) {
        l2 = qdv + qdkd[(b*T + j2)*16 + 8 + h] + escl[h][j2] + ba0;
        if (i >= 1) {
            float pr = prior[((size_t)bh*S + (i-1))*S + (j2-1)];
            pr = fminf(fmaxf(pr, 1e-6f), 1.f - 1e-6f);
            l2 += __logf(pr) - __logf(1.f - pr);
        }
    }

    float m = fmaxf(l1, l2);
    #pragma unroll
    for (int mm = 32; mm >= 1; mm >>= 1) m = fmaxf(m, __shfl_xor(m, mm));
    const float e1 = v1 ? __expf(l1 - m) : 0.f;
    const float e2 = v2 ? __expf(l2 - m) : 0.f;
    float s = e1 + e2;
    #pragma unroll
    for (int mm = 32; mm >= 1; mm >>= 1) s += __shfl_xor(s, mm);
    const float inv = 1.f / s;
    const float at1 = e1 * inv, at2 = e2 * inv;

    float* arow = out_attn + (size_t)(bh*T + i)*T;
    arow[j1] = at1;
    arow[j2] = at2;
    if (lane == 0) arow[0] = 0.f;
    pat[h][j1] = at1;
    pat[h][j2] = at2;
    __syncthreads();

    // ---- Phase C: ctx ----
    const int d = lane & 31, halfc = lane >> 5;
    float acc = 0.f;
    const float* vb = v + (size_t)(b*T)*D + h*HD + d;
    #pragma unroll 8
    for (int jj = 0; jj < 64; ++jj) {
        const int jc = 1 + halfc*64 + jj;
        acc = fmaf(pat[h][jc], vb[(size_t)jc * D], acc);
    }
    acc += __shfl_xor(acc, 32);
    if (lane < 32)
        out_basis[((size_t)(b*T + i)*H + h)*HD + d] = acc;
}

extern "C" void kernel_launch(void* const* d_in, const int* in_sizes, int n_in,
                              void* d_out, int out_size, void* d_ws, size_t ws_size,
                              hipStream_t stream) {
    const float* desc  = (const float*)d_in[0];
    const float* nv    = (const float*)d_in[1];
    const float* prior = (const float*)d_in[2];
    const float* Wq  = (const float*)d_in[3];
    const float* bq  = (const float*)d_in[4];
    const float* Wk  = (const float*)d_in[5];
    const float* bk  = (const float*)d_in[6];
    const float* Wv  = (const float*)d_in[7];
    const float* bv  = (const float*)d_in[8];
    const float* wa  = (const float*)d_in[9];
    const float* ba  = (const float*)d_in[10];
    const float* We1 = (const float*)d_in[11];
    const float* be1 = (const float*)d_in[12];
    const float* lng = (const float*)d_in[13];
    const float* lnb = (const float*)d_in[14];
    const float* We2 = (const float*)d_in[15];
    const float* be2 = (const float*)d_in[16];

    float* ws = (float*)d_ws;
    float* U    = ws; ws += B*S*D;
    float* V    = ws; ws += B*S*D;
    float* Vt   = ws; ws += B*D*S;
    float* v    = ws; ws += B*T*D;
    float* qdkd = ws; ws += B*T*16;
    float* W2ca = ws; ws += D*H;
    float* ec   = ws; ws += H;
    float* sU   = ws; ws += B*S;
    float* sU2  = ws; ws += B*S;
    float* sV   = ws; ws += B*S;
    float* sV2  = ws; ws += B*S;

    float* out_basis = (float*)d_out;
    float* out_attn  = out_basis + B*T*H*HD;

    gemm_all<<<dim3(836), 256, 0, stream>>>(nv, desc, Wq, bq, Wk, bk, Wv, bv,
                                            We1, be1, We2, be2, wa,
                                            v, U, V, Vt, qdkd, W2ca, ec,
                                            sU, sU2, sV, sV2);
    edge_attn<<<dim3(B*T), 512, 0, stream>>>(U, V, Vt, W2ca, ec, lng, lnb,
                                             qdkd, prior, v, ba,
                                             sU, sU2, sV, sV2,
                                             out_basis, out_attn);
}